// Round 1
// baseline (1105.882 us; speedup 1.0000x reference)
//
#include <hip/hip_runtime.h>
#include <math.h>

#define T_DIM 2048
#define B_DIM 2
#define E_DIM 1024
#define K_DIM 64
#define H_DIM 16
#define R_DIM (T_DIM * B_DIM)   // 4096 rows, row r = t*B + b

// ---------------------------------------------------------------------------
// GEMM: C[R x N] = X[R x 1024] * W[N x 1024]^T + bias[N]
// Both X and W are row-major with the contraction dim (1024) innermost ("NT"),
// so both tile loads are coalesced along k. Tiles 64x64, BK=32.
// ---------------------------------------------------------------------------
__global__ __launch_bounds__(256) void gemm_bias(const float* __restrict__ X,
                                                 const float* __restrict__ W,
                                                 const float* __restrict__ bias,
                                                 float* __restrict__ C, int N) {
    __shared__ float Xs[64][33];
    __shared__ float Ws[64][33];
    const int rBase = blockIdx.x * 64;
    const int cBase = blockIdx.y * 64;
    const int tid = threadIdx.x;
    const int tx = tid & 15;    // col group: cols cBase + tx*4 .. +3
    const int ty = tid >> 4;    // row group: rows rBase + ty*4 .. +3
    float c[4][4] = {{0.f}};

    for (int kk = 0; kk < E_DIM; kk += 32) {
        __syncthreads();
#pragma unroll
        for (int i = 0; i < 8; ++i) {
            int l = tid + i * 256;       // 2048 elements per tile
            int row = l >> 5, k = l & 31;
            Xs[row][k] = X[(size_t)(rBase + row) * E_DIM + kk + k];
            Ws[row][k] = W[(size_t)(cBase + row) * E_DIM + kk + k];
        }
        __syncthreads();
#pragma unroll
        for (int k = 0; k < 32; ++k) {
            float a[4], bv[4];
#pragma unroll
            for (int i = 0; i < 4; ++i) a[i] = Xs[ty * 4 + i][k];
#pragma unroll
            for (int j = 0; j < 4; ++j) bv[j] = Ws[tx * 4 + j][k];
#pragma unroll
            for (int i = 0; i < 4; ++i)
#pragma unroll
                for (int j = 0; j < 4; ++j) c[i][j] += a[i] * bv[j];
        }
    }
#pragma unroll
    for (int i = 0; i < 4; ++i) {
        int r = rBase + ty * 4 + i;
#pragma unroll
        for (int j = 0; j < 4; ++j) {
            int col = cBase + tx * 4 + j;
            C[(size_t)r * N + col] = c[i][j] + bias[col];
        }
    }
}

// ---------------------------------------------------------------------------
// qn[r, k] = mean_h softmax_k(q[r, h*64 + k]) ; one wave per row.
// ---------------------------------------------------------------------------
__global__ __launch_bounds__(64) void softmax_mean(const float* __restrict__ Q,
                                                   float* __restrict__ QN) {
    const int r = blockIdx.x;
    const int lane = threadIdx.x;
    float acc = 0.f;
#pragma unroll
    for (int h = 0; h < H_DIM; ++h) {
        float v = Q[(size_t)r * 1024 + h * 64 + lane];
        float m = v;
#pragma unroll
        for (int off = 32; off; off >>= 1) m = fmaxf(m, __shfl_xor(m, off));
        float e = expf(v - m);
        float ssum = e;
#pragma unroll
        for (int off = 32; off; off >>= 1) ssum += __shfl_xor(ssum, off);
        acc += e / ssum;
    }
    QN[(size_t)r * K_DIM + lane] = acc * (1.f / 16.f);
}

// ---------------------------------------------------------------------------
// LayerNorm over 64 (for k); one wave per row.
// ---------------------------------------------------------------------------
__global__ __launch_bounds__(64) void ln64(const float* __restrict__ Kraw,
                                           const float* __restrict__ gamma,
                                           const float* __restrict__ beta,
                                           float* __restrict__ KN) {
    const int r = blockIdx.x;
    const int lane = threadIdx.x;
    float v = Kraw[(size_t)r * K_DIM + lane];
    float s = v, s2 = v * v;
#pragma unroll
    for (int off = 32; off; off >>= 1) {
        s += __shfl_xor(s, off);
        s2 += __shfl_xor(s2, off);
    }
    float mean = s * (1.f / 64.f);
    float var = s2 * (1.f / 64.f) - mean * mean;
    float inv = rsqrtf(var + 1e-5f);
    KN[(size_t)r * K_DIM + lane] = (v - mean) * inv * gamma[lane] + beta[lane];
}

// ---------------------------------------------------------------------------
// LayerNorm over 1024 (for v), in place. Block = 256 threads (4 waves).
// ---------------------------------------------------------------------------
__global__ __launch_bounds__(256) void ln1024(float* __restrict__ V,
                                              const float* __restrict__ gamma,
                                              const float* __restrict__ beta) {
    const int r = blockIdx.x;
    const int tid = threadIdx.x;
    const int lane = tid & 63, wv = tid >> 6;
    float4 v = *(const float4*)&V[(size_t)r * E_DIM + tid * 4];
    float s = v.x + v.y + v.z + v.w;
    float s2 = v.x * v.x + v.y * v.y + v.z * v.z + v.w * v.w;
#pragma unroll
    for (int off = 32; off; off >>= 1) {
        s += __shfl_xor(s, off);
        s2 += __shfl_xor(s2, off);
    }
    __shared__ float red[2][4];
    if (lane == 0) { red[0][wv] = s; red[1][wv] = s2; }
    __syncthreads();
    s = red[0][0] + red[0][1] + red[0][2] + red[0][3];
    s2 = red[1][0] + red[1][1] + red[1][2] + red[1][3];
    float mean = s * (1.f / 1024.f);
    float var = s2 * (1.f / 1024.f) - mean * mean;
    float inv = rsqrtf(var + 1e-5f);
    float4 g = *(const float4*)&gamma[tid * 4];
    float4 bb = *(const float4*)&beta[tid * 4];
    float4 o;
    o.x = (v.x - mean) * inv * g.x + bb.x;
    o.y = (v.y - mean) * inv * g.y + bb.y;
    o.z = (v.z - mean) * inv * g.z + bb.z;
    o.w = (v.w - mean) * inv * g.w + bb.w;
    *(float4*)&V[(size_t)r * E_DIM + tid * 4] = o;
}

// ---------------------------------------------------------------------------
// Causal linear attention:
//   out[t,b,e] = rsqrt(t+1) * sum_{s<=t} (qn[t,b,:]·kn[s,b,:]) * v[s,b,e]
// Block: TQ=32 queries x EC=256 cols, one b. Paired q-tiles (qt, 63-qt) for
// equal work per block -> grid (32 pairs, 4 chunks, 2 b) = 256 blocks.
// ---------------------------------------------------------------------------
__global__ __launch_bounds__(256) void attn_kernel(const float* __restrict__ QN,
                                                   const float* __restrict__ KN,
                                                   const float* __restrict__ V,
                                                   float* __restrict__ OUT) {
    __shared__ __align__(16) float qs[32][68];
    __shared__ __align__(16) float ks[32][68];
    __shared__ float sc[32][33];
    const int pair = blockIdx.x;   // 0..31
    const int ec = blockIdx.y;     // 0..3
    const int b = blockIdx.z;      // 0..1
    const int tid = threadIdx.x;
    const int tx = tid & 31;       // cols ec*256 + tx*8 .. +7
    const int ty = tid >> 5;       // queries qt*32 + ty*4 .. +3

    for (int half = 0; half < 2; ++half) {
        const int qt = half ? (63 - pair) : pair;
        __syncthreads();
        for (int l = tid; l < 32 * 64; l += 256) {
            int qq = l >> 6, k = l & 63;
            qs[qq][k] = QN[((size_t)(qt * 32 + qq) * B_DIM + b) * K_DIM + k];
        }
        float acc[4][8];
#pragma unroll
        for (int i = 0; i < 4; ++i)
#pragma unroll
            for (int j = 0; j < 8; ++j) acc[i][j] = 0.f;

        const int nst = qt + 1;
        for (int st = 0; st < nst; ++st) {
            __syncthreads();
            for (int l = tid; l < 32 * 64; l += 256) {
                int ss = l >> 6, k = l & 63;
                ks[ss][k] = KN[((size_t)(st * 32 + ss) * B_DIM + b) * K_DIM + k];
            }
            __syncthreads();
            // scores: 32x32 dots of length 64; lane mapping qq=p&31, ss=p>>5
            // -> ks reads are wave-broadcast, qs reads conflict-free-ish.
#pragma unroll
            for (int i = 0; i < 4; ++i) {
                int p = tid + i * 256;
                int qq = p & 31, ss = p >> 5;
                float d = 0.f;
#pragma unroll
                for (int k = 0; k < 64; k += 4) {
                    float4 a = *(const float4*)&qs[qq][k];
                    float4 kb = *(const float4*)&ks[ss][k];
                    d += a.x * kb.x + a.y * kb.y + a.z * kb.z + a.w * kb.w;
                }
                int tg = qt * 32 + qq, sg = st * 32 + ss;
                sc[qq][ss] = (sg <= tg) ? d : 0.f;
            }
            __syncthreads();
            const float* vbase =
                V + ((size_t)(st * 32) * B_DIM + b) * E_DIM + ec * 256 + tx * 8;
#pragma unroll 4
            for (int ss = 0; ss < 32; ++ss) {
                float a0 = sc[ty * 4 + 0][ss];
                float a1 = sc[ty * 4 + 1][ss];
                float a2 = sc[ty * 4 + 2][ss];
                float a3 = sc[ty * 4 + 3][ss];
                const float* vp = vbase + (size_t)ss * B_DIM * E_DIM;
                float4 v0 = *(const float4*)vp;
                float4 v1 = *(const float4*)(vp + 4);
                float av[8] = {v0.x, v0.y, v0.z, v0.w, v1.x, v1.y, v1.z, v1.w};
#pragma unroll
                for (int j = 0; j < 8; ++j) {
                    acc[0][j] += a0 * av[j];
                    acc[1][j] += a1 * av[j];
                    acc[2][j] += a2 * av[j];
                    acc[3][j] += a3 * av[j];
                }
            }
        }
        // epilogue: per-query rsqrt(t+1) scaling, vectorized store
#pragma unroll
        for (int i = 0; i < 4; ++i) {
            int t = qt * 32 + ty * 4 + i;
            float sca = rsqrtf((float)(t + 1));
            float* o = OUT + ((size_t)t * B_DIM + b) * E_DIM + ec * 256 + tx * 8;
            float4 o0 = {acc[i][0] * sca, acc[i][1] * sca, acc[i][2] * sca,
                         acc[i][3] * sca};
            float4 o1 = {acc[i][4] * sca, acc[i][5] * sca, acc[i][6] * sca,
                         acc[i][7] * sca};
            *(float4*)o = o0;
            *(float4*)(o + 4) = o1;
        }
    }
}

// ---------------------------------------------------------------------------
extern "C" void kernel_launch(void* const* d_in, const int* in_sizes, int n_in,
                              void* d_out, int out_size, void* d_ws,
                              size_t ws_size, hipStream_t stream) {
    const float* x = (const float*)d_in[0];
    // d_in[1] = attn_mask: unused (causal mask is implicit in the cumsum)
    const float* Wq = (const float*)d_in[2];
    const float* bq = (const float*)d_in[3];
    const float* Wk = (const float*)d_in[4];
    const float* bk = (const float*)d_in[5];
    const float* Wv = (const float*)d_in[6];
    const float* bv = (const float*)d_in[7];
    const float* kg = (const float*)d_in[8];
    const float* kb = (const float*)d_in[9];
    const float* vg = (const float*)d_in[10];
    const float* vb = (const float*)d_in[11];
    float* out = (float*)d_out;

    float* ws = (float*)d_ws;
    float* qraw = ws;                              // 4M floats (16 MB)
    float* v = ws + (size_t)4 * 1024 * 1024;       // 4M floats (16 MB)
    float* qn = ws + (size_t)8 * 1024 * 1024;      // 256K floats
    float* kn = qn + 256 * 1024;                   // 256K floats
    float* kraw = kn + 256 * 1024;                 // 256K floats

    // projections
    gemm_bias<<<dim3(R_DIM / 64, E_DIM / 64), 256, 0, stream>>>(x, Wq, bq, qraw,
                                                                E_DIM);
    gemm_bias<<<dim3(R_DIM / 64, 1), 256, 0, stream>>>(x, Wk, bk, kraw, K_DIM);
    gemm_bias<<<dim3(R_DIM / 64, E_DIM / 64), 256, 0, stream>>>(x, Wv, bv, v,
                                                                E_DIM);
    // epilogues
    softmax_mean<<<dim3(R_DIM), 64, 0, stream>>>(qraw, qn);
    ln64<<<dim3(R_DIM), 64, 0, stream>>>(kraw, kg, kb, kn);
    ln1024<<<dim3(R_DIM), 256, 0, stream>>>(v, vg, vb);
    // causal linear attention
    attn_kernel<<<dim3(32, 4, 2), 256, 0, stream>>>(qn, kn, v, out);
}

// Round 2
// 628.020 us; speedup vs baseline: 1.7609x; 1.7609x over previous
//
#include <hip/hip_runtime.h>
#include <math.h>

#define T_DIM 2048
#define B_DIM 2
#define E_DIM 1024
#define K_DIM 64
#define H_DIM 16
#define R_DIM (T_DIM * B_DIM)   // 4096 rows, row r = t*B + b
#define CHUNK 128               // state chunk (4 sub-tiles of 32)
#define NC (T_DIM / CHUNK)      // 16 chunks

// ---------------------------------------------------------------------------
// GEMM: C[R x N] = X[R x 1024] * W[N x 1024]^T + bias[N]  (fp32, 64x64 tiles)
// ---------------------------------------------------------------------------
__global__ __launch_bounds__(256) void gemm_bias(const float* __restrict__ X,
                                                 const float* __restrict__ W,
                                                 const float* __restrict__ bias,
                                                 float* __restrict__ C, int N) {
    __shared__ float Xs[64][33];
    __shared__ float Ws[64][33];
    const int rBase = blockIdx.x * 64;
    const int cBase = blockIdx.y * 64;
    const int tid = threadIdx.x;
    const int tx = tid & 15;
    const int ty = tid >> 4;
    float c[4][4] = {{0.f}};

    for (int kk = 0; kk < E_DIM; kk += 32) {
        __syncthreads();
#pragma unroll
        for (int i = 0; i < 8; ++i) {
            int l = tid + i * 256;
            int row = l >> 5, k = l & 31;
            Xs[row][k] = X[(size_t)(rBase + row) * E_DIM + kk + k];
            Ws[row][k] = W[(size_t)(cBase + row) * E_DIM + kk + k];
        }
        __syncthreads();
#pragma unroll
        for (int k = 0; k < 32; ++k) {
            float a[4], bv[4];
#pragma unroll
            for (int i = 0; i < 4; ++i) a[i] = Xs[ty * 4 + i][k];
#pragma unroll
            for (int j = 0; j < 4; ++j) bv[j] = Ws[tx * 4 + j][k];
#pragma unroll
            for (int i = 0; i < 4; ++i)
#pragma unroll
                for (int j = 0; j < 4; ++j) c[i][j] += a[i] * bv[j];
        }
    }
#pragma unroll
    for (int i = 0; i < 4; ++i) {
        int r = rBase + ty * 4 + i;
#pragma unroll
        for (int j = 0; j < 4; ++j) {
            int col = cBase + tx * 4 + j;
            C[(size_t)r * N + col] = c[i][j] + bias[col];
        }
    }
}

// ---------------------------------------------------------------------------
// qn[r, k] = mean_h softmax_k(q[r, h*64 + k]) ; one wave per row.
// ---------------------------------------------------------------------------
__global__ __launch_bounds__(64) void softmax_mean(const float* __restrict__ Q,
                                                   float* __restrict__ QN) {
    const int r = blockIdx.x;
    const int lane = threadIdx.x;
    float acc = 0.f;
#pragma unroll
    for (int h = 0; h < H_DIM; ++h) {
        float v = Q[(size_t)r * 1024 + h * 64 + lane];
        float m = v;
#pragma unroll
        for (int off = 32; off; off >>= 1) m = fmaxf(m, __shfl_xor(m, off));
        float e = expf(v - m);
        float ssum = e;
#pragma unroll
        for (int off = 32; off; off >>= 1) ssum += __shfl_xor(ssum, off);
        acc += e / ssum;
    }
    QN[(size_t)r * K_DIM + lane] = acc * (1.f / 16.f);
}

// ---------------------------------------------------------------------------
// LayerNorm over 64 (for k); one wave per row.
// ---------------------------------------------------------------------------
__global__ __launch_bounds__(64) void ln64(const float* __restrict__ Kraw,
                                           const float* __restrict__ gamma,
                                           const float* __restrict__ beta,
                                           float* __restrict__ KN) {
    const int r = blockIdx.x;
    const int lane = threadIdx.x;
    float v = Kraw[(size_t)r * K_DIM + lane];
    float s = v, s2 = v * v;
#pragma unroll
    for (int off = 32; off; off >>= 1) {
        s += __shfl_xor(s, off);
        s2 += __shfl_xor(s2, off);
    }
    float mean = s * (1.f / 64.f);
    float var = s2 * (1.f / 64.f) - mean * mean;
    float inv = rsqrtf(var + 1e-5f);
    KN[(size_t)r * K_DIM + lane] = (v - mean) * inv * gamma[lane] + beta[lane];
}

// ---------------------------------------------------------------------------
// LayerNorm over 1024 (for v), in place. Block = 256 threads.
// ---------------------------------------------------------------------------
__global__ __launch_bounds__(256) void ln1024(float* __restrict__ V,
                                              const float* __restrict__ gamma,
                                              const float* __restrict__ beta) {
    const int r = blockIdx.x;
    const int tid = threadIdx.x;
    const int lane = tid & 63, wv = tid >> 6;
    float4 v = *(const float4*)&V[(size_t)r * E_DIM + tid * 4];
    float s = v.x + v.y + v.z + v.w;
    float s2 = v.x * v.x + v.y * v.y + v.z * v.z + v.w * v.w;
#pragma unroll
    for (int off = 32; off; off >>= 1) {
        s += __shfl_xor(s, off);
        s2 += __shfl_xor(s2, off);
    }
    __shared__ float red[2][4];
    if (lane == 0) { red[0][wv] = s; red[1][wv] = s2; }
    __syncthreads();
    s = red[0][0] + red[0][1] + red[0][2] + red[0][3];
    s2 = red[1][0] + red[1][1] + red[1][2] + red[1][3];
    float mean = s * (1.f / 1024.f);
    float var = s2 * (1.f / 1024.f) - mean * mean;
    float inv = rsqrtf(var + 1e-5f);
    float4 g = *(const float4*)&gamma[tid * 4];
    float4 bb = *(const float4*)&beta[tid * 4];
    float4 o;
    o.x = (v.x - mean) * inv * g.x + bb.x;
    o.y = (v.y - mean) * inv * g.y + bb.y;
    o.z = (v.z - mean) * inv * g.z + bb.z;
    o.w = (v.w - mean) * inv * g.w + bb.w;
    *(float4*)&V[(size_t)r * E_DIM + tid * 4] = o;
}

// ---------------------------------------------------------------------------
// Pass A: per-chunk outer products O_c[b][k][e] = sum_{s in chunk} kn[s,k]*v[s,e]
// Grid (NC, 4 e-slices of 256, B). Block 256 threads: ex=tid&63 (4 e each),
// kg=tid>>6 (16 k each). acc[16][4].
// ---------------------------------------------------------------------------
__global__ __launch_bounds__(256) void chunk_outer(const float* __restrict__ KN,
                                                   const float* __restrict__ V,
                                                   float* __restrict__ O) {
    __shared__ __align__(16) float ks_l[CHUNK][64];   // 32 KB
    __shared__ __align__(16) float vs[16][256];       // 16 KB
    const int c = blockIdx.x, es = blockIdx.y, b = blockIdx.z;
    const int tid = threadIdx.x;
    const int ex = tid & 63;     // e = es*256 + ex*4
    const int kg = tid >> 6;     // k rows kg*16 .. +15

    // stage kn chunk [128][64]
#pragma unroll
    for (int j = 0; j < 8; ++j) {
        int idx = tid + j * 256;           // float4 id, 2048 total
        int s = idx >> 4, k4 = idx & 15;
        *(float4*)&ks_l[s][k4 * 4] =
            *(const float4*)&KN[((size_t)(c * CHUNK + s) * B_DIM + b) * K_DIM + k4 * 4];
    }
    float acc[16][4];
#pragma unroll
    for (int i = 0; i < 16; ++i)
#pragma unroll
        for (int j = 0; j < 4; ++j) acc[i][j] = 0.f;

    for (int sb = 0; sb < CHUNK / 16; ++sb) {
        __syncthreads();
#pragma unroll
        for (int j = 0; j < 4; ++j) {
            int idx = tid + j * 256;       // float4 id, 1024 total
            int s = idx >> 6, e4 = idx & 63;
            *(float4*)&vs[s][e4 * 4] =
                *(const float4*)&V[((size_t)(c * CHUNK + sb * 16 + s) * B_DIM + b) * E_DIM +
                                   es * 256 + e4 * 4];
        }
        __syncthreads();
#pragma unroll
        for (int s = 0; s < 16; ++s) {
            float4 vv = *(const float4*)&vs[s][ex * 4];
#pragma unroll
            for (int i4 = 0; i4 < 4; ++i4) {
                float4 kv = *(const float4*)&ks_l[sb * 16 + s][kg * 16 + i4 * 4];
                float ka[4] = {kv.x, kv.y, kv.z, kv.w};
#pragma unroll
                for (int u = 0; u < 4; ++u) {
                    acc[i4 * 4 + u][0] += ka[u] * vv.x;
                    acc[i4 * 4 + u][1] += ka[u] * vv.y;
                    acc[i4 * 4 + u][2] += ka[u] * vv.z;
                    acc[i4 * 4 + u][3] += ka[u] * vv.w;
                }
            }
        }
    }
#pragma unroll
    for (int i = 0; i < 16; ++i) {
        int k = kg * 16 + i;
        float4 o = {acc[i][0], acc[i][1], acc[i][2], acc[i][3]};
        *(float4*)&O[(((size_t)c * B_DIM + b) * K_DIM + k) * E_DIM + es * 256 + ex * 4] = o;
    }
}

// ---------------------------------------------------------------------------
// Pass B: exclusive prefix over chunks: S_c = sum_{c'<c} O_c'
// One thread per float4 of [B][K][E]. 32768 threads.
// ---------------------------------------------------------------------------
__global__ __launch_bounds__(256) void prefix_state(const float* __restrict__ O,
                                                    float* __restrict__ S) {
    const size_t p = (size_t)blockIdx.x * 256 + threadIdx.x;   // float4 id
    const size_t off = p * 4;                                  // within B*K*E
    const size_t cs = (size_t)B_DIM * K_DIM * E_DIM;           // 131072
    float4 run = {0.f, 0.f, 0.f, 0.f};
    for (int c = 0; c < NC; ++c) {
        *(float4*)&S[c * cs + off] = run;
        float4 o = *(const float4*)&O[c * cs + off];
        run.x += o.x; run.y += o.y; run.z += o.z; run.w += o.w;
    }
}

// ---------------------------------------------------------------------------
// Pass C2: intra-chunk causal part (unscaled):
//   out[t,b,e] = sum_{s in chunk(t), s<=t} (qn[t]·kn[s]) v[s,e]
// Grid (64 q-tiles of 32, 4 e-slices of 256, B). <=4 s-sub-tiles per block.
// ---------------------------------------------------------------------------
__global__ __launch_bounds__(256) void intra_attn(const float* __restrict__ QN,
                                                  const float* __restrict__ KN,
                                                  const float* __restrict__ V,
                                                  float* __restrict__ OUT) {
    __shared__ __align__(16) float qs[32][68];
    __shared__ __align__(16) float ks[32][68];
    __shared__ float sc[32][33];
    const int qt = blockIdx.x;     // 0..63
    const int ec = blockIdx.y;     // 0..3
    const int b = blockIdx.z;
    const int tid = threadIdx.x;
    const int tx = tid & 31;       // cols ec*256 + tx*8 .. +7
    const int ty = tid >> 5;       // queries qt*32 + ty*4 .. +3

    for (int l = tid; l < 32 * 64; l += 256) {
        int qq = l >> 6, k = l & 63;
        qs[qq][k] = QN[((size_t)(qt * 32 + qq) * B_DIM + b) * K_DIM + k];
    }
    float acc[4][8];
#pragma unroll
    for (int i = 0; i < 4; ++i)
#pragma unroll
        for (int j = 0; j < 8; ++j) acc[i][j] = 0.f;

    const int st0 = qt & ~3;       // first sub-tile of this 128-chunk
    for (int st = st0; st <= qt; ++st) {
        __syncthreads();
        for (int l = tid; l < 32 * 64; l += 256) {
            int ss = l >> 6, k = l & 63;
            ks[ss][k] = KN[((size_t)(st * 32 + ss) * B_DIM + b) * K_DIM + k];
        }
        __syncthreads();
#pragma unroll
        for (int i = 0; i < 4; ++i) {
            int p = tid + i * 256;
            int qq = p & 31, ss = p >> 5;
            float d = 0.f;
#pragma unroll
            for (int k = 0; k < 64; k += 4) {
                float4 a = *(const float4*)&qs[qq][k];
                float4 kb = *(const float4*)&ks[ss][k];
                d += a.x * kb.x + a.y * kb.y + a.z * kb.z + a.w * kb.w;
            }
            int tg = qt * 32 + qq, sg = st * 32 + ss;
            sc[qq][ss] = (sg <= tg) ? d : 0.f;
        }
        __syncthreads();
        const float* vbase =
            V + ((size_t)(st * 32) * B_DIM + b) * E_DIM + ec * 256 + tx * 8;
#pragma unroll 4
        for (int ss = 0; ss < 32; ++ss) {
            float a0 = sc[ty * 4 + 0][ss];
            float a1 = sc[ty * 4 + 1][ss];
            float a2 = sc[ty * 4 + 2][ss];
            float a3 = sc[ty * 4 + 3][ss];
            const float* vp = vbase + (size_t)ss * B_DIM * E_DIM;
            float4 v0 = *(const float4*)vp;
            float4 v1 = *(const float4*)(vp + 4);
            float av[8] = {v0.x, v0.y, v0.z, v0.w, v1.x, v1.y, v1.z, v1.w};
#pragma unroll
            for (int j = 0; j < 8; ++j) {
                acc[0][j] += a0 * av[j];
                acc[1][j] += a1 * av[j];
                acc[2][j] += a2 * av[j];
                acc[3][j] += a3 * av[j];
            }
        }
        __syncthreads();
    }
#pragma unroll
    for (int i = 0; i < 4; ++i) {
        int t = qt * 32 + ty * 4 + i;
        float* o = OUT + ((size_t)t * B_DIM + b) * E_DIM + ec * 256 + tx * 8;
        float4 o0 = {acc[i][0], acc[i][1], acc[i][2], acc[i][3]};
        float4 o1 = {acc[i][4], acc[i][5], acc[i][6], acc[i][7]};
        *(float4*)o = o0;
        *(float4*)(o + 4) = o1;
    }
}

// ---------------------------------------------------------------------------
// Pass C1: out = (out + qn @ S_chunk(t)) * rsqrt(t+1)
// Grid (32 t-tiles of 64, 8 e-slices of 128, B). Block 256: ex=tid&31 (4 e),
// tg=tid>>5 (8 t rows each). acc[8][4].
// ---------------------------------------------------------------------------
__global__ __launch_bounds__(256) void inter_add(const float* __restrict__ QN,
                                                 const float* __restrict__ S,
                                                 float* __restrict__ OUT) {
    __shared__ __align__(16) float Sl[64][128];    // 32 KB
    __shared__ __align__(16) float qs[64][64];     // 16 KB
    const int tt = blockIdx.x;         // t0 = tt*64
    const int es = blockIdx.y;         // e0 = es*128
    const int b = blockIdx.z;
    const int tid = threadIdx.x;
    const int ex = tid & 31;
    const int tg = tid >> 5;
    const int t0 = tt * 64;
    const int c = t0 / CHUNK;
    const size_t cs = (size_t)B_DIM * K_DIM * E_DIM;

    // stage S_c slice [64 k][128 e]
#pragma unroll
    for (int j = 0; j < 8; ++j) {
        int idx = tid + j * 256;          // float4 id, 2048 total
        int k = idx >> 5, e4 = idx & 31;
        *(float4*)&Sl[k][e4 * 4] =
            *(const float4*)&S[c * cs + ((size_t)b * K_DIM + k) * E_DIM + es * 128 + e4 * 4];
    }
    // stage qn tile [64 t][64 k]
#pragma unroll
    for (int j = 0; j < 4; ++j) {
        int idx = tid + j * 256;          // float4 id, 1024 total
        int t = idx >> 4, k4 = idx & 15;
        *(float4*)&qs[t][k4 * 4] =
            *(const float4*)&QN[((size_t)(t0 + t) * B_DIM + b) * K_DIM + k4 * 4];
    }
    __syncthreads();

    float acc[8][4];
#pragma unroll
    for (int i = 0; i < 8; ++i)
#pragma unroll
        for (int j = 0; j < 4; ++j) acc[i][j] = 0.f;

#pragma unroll 4
    for (int k = 0; k < 64; k += 4) {
        float4 sv0 = *(const float4*)&Sl[k + 0][ex * 4];
        float4 sv1 = *(const float4*)&Sl[k + 1][ex * 4];
        float4 sv2 = *(const float4*)&Sl[k + 2][ex * 4];
        float4 sv3 = *(const float4*)&Sl[k + 3][ex * 4];
#pragma unroll
        for (int i = 0; i < 8; ++i) {
            float4 qv = *(const float4*)&qs[tg * 8 + i][k];
            acc[i][0] += qv.x * sv0.x + qv.y * sv1.x + qv.z * sv2.x + qv.w * sv3.x;
            acc[i][1] += qv.x * sv0.y + qv.y * sv1.y + qv.z * sv2.y + qv.w * sv3.y;
            acc[i][2] += qv.x * sv0.z + qv.y * sv1.z + qv.z * sv2.z + qv.w * sv3.z;
            acc[i][3] += qv.x * sv0.w + qv.y * sv1.w + qv.z * sv2.w + qv.w * sv3.w;
        }
    }
#pragma unroll
    for (int i = 0; i < 8; ++i) {
        int t = t0 + tg * 8 + i;
        float sca = rsqrtf((float)(t + 1));
        float* o = OUT + ((size_t)t * B_DIM + b) * E_DIM + es * 128 + ex * 4;
        float4 prev = *(const float4*)o;
        float4 r;
        r.x = (prev.x + acc[i][0]) * sca;
        r.y = (prev.y + acc[i][1]) * sca;
        r.z = (prev.z + acc[i][2]) * sca;
        r.w = (prev.w + acc[i][3]) * sca;
        *(float4*)o = r;
    }
}

// ---------------------------------------------------------------------------
extern "C" void kernel_launch(void* const* d_in, const int* in_sizes, int n_in,
                              void* d_out, int out_size, void* d_ws,
                              size_t ws_size, hipStream_t stream) {
    const float* x = (const float*)d_in[0];
    const float* Wq = (const float*)d_in[2];
    const float* bq = (const float*)d_in[3];
    const float* Wk = (const float*)d_in[4];
    const float* bk = (const float*)d_in[5];
    const float* Wv = (const float*)d_in[6];
    const float* bv = (const float*)d_in[7];
    const float* kg = (const float*)d_in[8];
    const float* kb = (const float*)d_in[9];
    const float* vg = (const float*)d_in[10];
    const float* vb = (const float*)d_in[11];
    float* out = (float*)d_out;

    float* ws = (float*)d_ws;
    float* qraw = ws;                              // 4M floats (16 MB)
    float* v = ws + (size_t)4 * 1024 * 1024;       // 4M floats (16 MB)
    float* qn = ws + (size_t)8 * 1024 * 1024;      // 256K floats
    float* kn = qn + 256 * 1024;                   // 256K floats
    float* kraw = kn + 256 * 1024;                 // 256K floats
    // qraw is free after softmax_mean: reuse for chunk states
    float* O = qraw;                               // NC*B*K*E = 2M floats
    float* S = qraw + (size_t)2 * 1024 * 1024;     // 2M floats

    // projections
    gemm_bias<<<dim3(R_DIM / 64, E_DIM / 64), 256, 0, stream>>>(x, Wq, bq, qraw, E_DIM);
    gemm_bias<<<dim3(R_DIM / 64, 1), 256, 0, stream>>>(x, Wk, bk, kraw, K_DIM);
    gemm_bias<<<dim3(R_DIM / 64, E_DIM / 64), 256, 0, stream>>>(x, Wv, bv, v, E_DIM);
    // epilogues
    softmax_mean<<<dim3(R_DIM), 64, 0, stream>>>(qraw, qn);
    ln64<<<dim3(R_DIM), 64, 0, stream>>>(kraw, kg, kb, kn);
    ln1024<<<dim3(R_DIM), 256, 0, stream>>>(v, vg, vb);
    // chunked linear attention
    chunk_outer<<<dim3(NC, 4, B_DIM), 256, 0, stream>>>(kn, v, O);
    prefix_state<<<dim3(128), 256, 0, stream>>>(O, S);
    intra_attn<<<dim3(64, 4, B_DIM), 256, 0, stream>>>(qn, kn, v, out);
    inter_add<<<dim3(32, 8, B_DIM), 256, 0, stream>>>(qn, S, out);
}

// Round 3
// 302.142 us; speedup vs baseline: 3.6601x; 2.0786x over previous
//
#include <hip/hip_runtime.h>
#include <math.h>

#define T_DIM 2048
#define B_DIM 2
#define E_DIM 1024
#define K_DIM 64
#define H_DIM 16
#define R_DIM (T_DIM * B_DIM)   // 4096 rows, row r = t*B + b
#define CHUNK 128               // state chunk (4 sub-tiles of 32)
#define NC (T_DIM / CHUNK)      // 16 chunks

typedef __bf16 bf16x8 __attribute__((ext_vector_type(8)));
typedef float f32x4 __attribute__((ext_vector_type(4)));

// ---------------------------------------------------------------------------
// fp32 -> bf16 conversion; reads A for g<nA else B (both float4x2 per thread).
// ---------------------------------------------------------------------------
__global__ __launch_bounds__(256) void cvt_pair(const float* __restrict__ A,
                                                const float* __restrict__ B,
                                                size_t nA,
                                                __bf16* __restrict__ O) {
    size_t g = ((size_t)blockIdx.x * 256 + threadIdx.x) * 8;
    const float* src;
    size_t off;
    if (g < nA) { src = A; off = g; } else { src = B; off = g - nA; }
    float4 a = *(const float4*)&src[off];
    float4 b = *(const float4*)&src[off + 4];
    bf16x8 o;
    o[0] = (__bf16)a.x; o[1] = (__bf16)a.y; o[2] = (__bf16)a.z; o[3] = (__bf16)a.w;
    o[4] = (__bf16)b.x; o[5] = (__bf16)b.y; o[6] = (__bf16)b.z; o[7] = (__bf16)b.w;
    *(bf16x8*)&O[g] = o;
}

// ---------------------------------------------------------------------------
// bf16 MFMA GEMM (m97 structure): C[4096 x 2048] = XB[4096x1024] @ WB[2048x1024]^T
// 128x128 tile, BK=32, 4 waves each owning 64x64 (4x4 MFMA tiles 16x16x32).
// Columns < 1024 -> Cq (+bq), >= 1024 -> Cv (+bv). Both outputs stride 1024.
// ---------------------------------------------------------------------------
__global__ __launch_bounds__(256) void gemm_mfma(const __bf16* __restrict__ XB,
                                                 const __bf16* __restrict__ WB,
                                                 const float* __restrict__ bq,
                                                 const float* __restrict__ bv,
                                                 float* __restrict__ Cq,
                                                 float* __restrict__ Cv) {
    __shared__ __bf16 Als[128 * 32];   // 8 KB
    __shared__ __bf16 Bls[128 * 32];   // 8 KB
    const int tid = threadIdx.x;
    const int lane = tid & 63;
    const int w = tid >> 6;
    const int wm = (w & 1) * 64;
    const int wn = (w >> 1) * 64;
    const int rBase = blockIdx.x * 128;
    const int cBase = blockIdx.y * 128;

    // staging: chunk c covers 16 B at LDS offset c*16; row=c>>2, koff=(c&3)*8.
    // Within a wave c = (wave-uniform) + lane, so LDS dest = base + lane*16. OK.
    const int c0 = tid, c1 = tid + 256;
    const __bf16* gA0 = XB + (size_t)(rBase + (c0 >> 2)) * E_DIM + (c0 & 3) * 8;
    const __bf16* gA1 = XB + (size_t)(rBase + (c1 >> 2)) * E_DIM + (c1 & 3) * 8;
    const __bf16* gB0 = WB + (size_t)(cBase + (c0 >> 2)) * E_DIM + (c0 & 3) * 8;
    const __bf16* gB1 = WB + (size_t)(cBase + (c1 >> 2)) * E_DIM + (c1 & 3) * 8;
    __bf16* lA0 = Als + c0 * 8;
    __bf16* lA1 = Als + c1 * 8;
    __bf16* lB0 = Bls + c0 * 8;
    __bf16* lB1 = Bls + c1 * 8;

    // fragment read base: lane -> A[m = lane&15][k = (lane>>4)*8 + 0..7]
    const int fr = lane & 15;
    const int fk = (lane >> 4) * 8;
    const __bf16* aF = Als + (wm + fr) * 32 + fk;
    const __bf16* bF = Bls + (wn + fr) * 32 + fk;

    f32x4 acc[4][4] = {};

    for (int kk = 0; kk < E_DIM; kk += 32) {
        __syncthreads();
        __builtin_amdgcn_global_load_lds(
            (const __attribute__((address_space(1))) void*)(gA0 + kk),
            (__attribute__((address_space(3))) void*)lA0, 16, 0, 0);
        __builtin_amdgcn_global_load_lds(
            (const __attribute__((address_space(1))) void*)(gA1 + kk),
            (__attribute__((address_space(3))) void*)lA1, 16, 0, 0);
        __builtin_amdgcn_global_load_lds(
            (const __attribute__((address_space(1))) void*)(gB0 + kk),
            (__attribute__((address_space(3))) void*)lB0, 16, 0, 0);
        __builtin_amdgcn_global_load_lds(
            (const __attribute__((address_space(1))) void*)(gB1 + kk),
            (__attribute__((address_space(3))) void*)lB1, 16, 0, 0);
        __syncthreads();

        bf16x8 af[4], bfr[4];
#pragma unroll
        for (int mt = 0; mt < 4; ++mt) af[mt] = *(const bf16x8*)(aF + mt * 16 * 32);
#pragma unroll
        for (int nt = 0; nt < 4; ++nt) bfr[nt] = *(const bf16x8*)(bF + nt * 16 * 32);
#pragma unroll
        for (int mt = 0; mt < 4; ++mt)
#pragma unroll
            for (int nt = 0; nt < 4; ++nt)
                acc[mt][nt] = __builtin_amdgcn_mfma_f32_16x16x32_bf16(
                    af[mt], bfr[nt], acc[mt][nt], 0, 0, 0);
    }

    // epilogue: C/D layout col=lane&15, row=(lane>>4)*4+reg
    const float* bias;
    float* Cout;
    int colBase;
    if (cBase < 1024) { bias = bq; Cout = Cq; colBase = cBase; }
    else              { bias = bv; Cout = Cv; colBase = cBase - 1024; }
    const int row0 = rBase + wm + (lane >> 4) * 4;
    const int col0 = colBase + wn + (lane & 15);
#pragma unroll
    for (int mt = 0; mt < 4; ++mt)
#pragma unroll
        for (int nt = 0; nt < 4; ++nt) {
            int cc = col0 + nt * 16;
            float bb = bias[cc];
#pragma unroll
            for (int r = 0; r < 4; ++r)
                Cout[(size_t)(row0 + mt * 16 + r) * E_DIM + cc] =
                    acc[mt][nt][r] + bb;
        }
}

// ---------------------------------------------------------------------------
// fp32 GEMM (kept for the small k projection): C[R x N] = X @ W^T + bias
// ---------------------------------------------------------------------------
__global__ __launch_bounds__(256) void gemm_bias(const float* __restrict__ X,
                                                 const float* __restrict__ W,
                                                 const float* __restrict__ bias,
                                                 float* __restrict__ C, int N) {
    __shared__ float Xs[64][33];
    __shared__ float Ws[64][33];
    const int rBase = blockIdx.x * 64;
    const int cBase = blockIdx.y * 64;
    const int tid = threadIdx.x;
    const int tx = tid & 15;
    const int ty = tid >> 4;
    float c[4][4] = {{0.f}};

    for (int kk = 0; kk < E_DIM; kk += 32) {
        __syncthreads();
#pragma unroll
        for (int i = 0; i < 8; ++i) {
            int l = tid + i * 256;
            int row = l >> 5, k = l & 31;
            Xs[row][k] = X[(size_t)(rBase + row) * E_DIM + kk + k];
            Ws[row][k] = W[(size_t)(cBase + row) * E_DIM + kk + k];
        }
        __syncthreads();
#pragma unroll
        for (int k = 0; k < 32; ++k) {
            float a[4], bv[4];
#pragma unroll
            for (int i = 0; i < 4; ++i) a[i] = Xs[ty * 4 + i][k];
#pragma unroll
            for (int j = 0; j < 4; ++j) bv[j] = Ws[tx * 4 + j][k];
#pragma unroll
            for (int i = 0; i < 4; ++i)
#pragma unroll
                for (int j = 0; j < 4; ++j) c[i][j] += a[i] * bv[j];
        }
    }
#pragma unroll
    for (int i = 0; i < 4; ++i) {
        int r = rBase + ty * 4 + i;
#pragma unroll
        for (int j = 0; j < 4; ++j) {
            int col = cBase + tx * 4 + j;
            C[(size_t)r * N + col] = c[i][j] + bias[col];
        }
    }
}

// ---------------------------------------------------------------------------
// qn[r, k] = mean_h softmax_k(q[r, h*64 + k]) ; one wave per row.
// ---------------------------------------------------------------------------
__global__ __launch_bounds__(64) void softmax_mean(const float* __restrict__ Q,
                                                   float* __restrict__ QN) {
    const int r = blockIdx.x;
    const int lane = threadIdx.x;
    float acc = 0.f;
#pragma unroll
    for (int h = 0; h < H_DIM; ++h) {
        float v = Q[(size_t)r * 1024 + h * 64 + lane];
        float m = v;
#pragma unroll
        for (int off = 32; off; off >>= 1) m = fmaxf(m, __shfl_xor(m, off));
        float e = expf(v - m);
        float ssum = e;
#pragma unroll
        for (int off = 32; off; off >>= 1) ssum += __shfl_xor(ssum, off);
        acc += e / ssum;
    }
    QN[(size_t)r * K_DIM + lane] = acc * (1.f / 16.f);
}

// ---------------------------------------------------------------------------
// LayerNorm over 64 (for k); one wave per row.
// ---------------------------------------------------------------------------
__global__ __launch_bounds__(64) void ln64(const float* __restrict__ Kraw,
                                           const float* __restrict__ gamma,
                                           const float* __restrict__ beta,
                                           float* __restrict__ KN) {
    const int r = blockIdx.x;
    const int lane = threadIdx.x;
    float v = Kraw[(size_t)r * K_DIM + lane];
    float s = v, s2 = v * v;
#pragma unroll
    for (int off = 32; off; off >>= 1) {
        s += __shfl_xor(s, off);
        s2 += __shfl_xor(s2, off);
    }
    float mean = s * (1.f / 64.f);
    float var = s2 * (1.f / 64.f) - mean * mean;
    float inv = rsqrtf(var + 1e-5f);
    KN[(size_t)r * K_DIM + lane] = (v - mean) * inv * gamma[lane] + beta[lane];
}

// ---------------------------------------------------------------------------
// LayerNorm over 1024 (for v), in place. Block = 256 threads.
// ---------------------------------------------------------------------------
__global__ __launch_bounds__(256) void ln1024(float* __restrict__ V,
                                              const float* __restrict__ gamma,
                                              const float* __restrict__ beta) {
    const int r = blockIdx.x;
    const int tid = threadIdx.x;
    const int lane = tid & 63, wv = tid >> 6;
    float4 v = *(const float4*)&V[(size_t)r * E_DIM + tid * 4];
    float s = v.x + v.y + v.z + v.w;
    float s2 = v.x * v.x + v.y * v.y + v.z * v.z + v.w * v.w;
#pragma unroll
    for (int off = 32; off; off >>= 1) {
        s += __shfl_xor(s, off);
        s2 += __shfl_xor(s2, off);
    }
    __shared__ float red[2][4];
    if (lane == 0) { red[0][wv] = s; red[1][wv] = s2; }
    __syncthreads();
    s = red[0][0] + red[0][1] + red[0][2] + red[0][3];
    s2 = red[1][0] + red[1][1] + red[1][2] + red[1][3];
    float mean = s * (1.f / 1024.f);
    float var = s2 * (1.f / 1024.f) - mean * mean;
    float inv = rsqrtf(var + 1e-5f);
    float4 g = *(const float4*)&gamma[tid * 4];
    float4 bb = *(const float4*)&beta[tid * 4];
    float4 o;
    o.x = (v.x - mean) * inv * g.x + bb.x;
    o.y = (v.y - mean) * inv * g.y + bb.y;
    o.z = (v.z - mean) * inv * g.z + bb.z;
    o.w = (v.w - mean) * inv * g.w + bb.w;
    *(float4*)&V[(size_t)r * E_DIM + tid * 4] = o;
}

// ---------------------------------------------------------------------------
// Pass A: per-chunk outer products O_c[b][k][e] = sum_{s in chunk} kn[s,k]*v[s,e]
// ---------------------------------------------------------------------------
__global__ __launch_bounds__(256) void chunk_outer(const float* __restrict__ KN,
                                                   const float* __restrict__ V,
                                                   float* __restrict__ O) {
    __shared__ __align__(16) float ks_l[CHUNK][64];   // 32 KB
    __shared__ __align__(16) float vs[16][256];       // 16 KB
    const int c = blockIdx.x, es = blockIdx.y, b = blockIdx.z;
    const int tid = threadIdx.x;
    const int ex = tid & 63;     // e = es*256 + ex*4
    const int kg = tid >> 6;     // k rows kg*16 .. +15

#pragma unroll
    for (int j = 0; j < 8; ++j) {
        int idx = tid + j * 256;
        int s = idx >> 4, k4 = idx & 15;
        *(float4*)&ks_l[s][k4 * 4] =
            *(const float4*)&KN[((size_t)(c * CHUNK + s) * B_DIM + b) * K_DIM + k4 * 4];
    }
    float acc[16][4];
#pragma unroll
    for (int i = 0; i < 16; ++i)
#pragma unroll
        for (int j = 0; j < 4; ++j) acc[i][j] = 0.f;

    for (int sb = 0; sb < CHUNK / 16; ++sb) {
        __syncthreads();
#pragma unroll
        for (int j = 0; j < 4; ++j) {
            int idx = tid + j * 256;
            int s = idx >> 6, e4 = idx & 63;
            *(float4*)&vs[s][e4 * 4] =
                *(const float4*)&V[((size_t)(c * CHUNK + sb * 16 + s) * B_DIM + b) * E_DIM +
                                   es * 256 + e4 * 4];
        }
        __syncthreads();
#pragma unroll
        for (int s = 0; s < 16; ++s) {
            float4 vv = *(const float4*)&vs[s][ex * 4];
#pragma unroll
            for (int i4 = 0; i4 < 4; ++i4) {
                float4 kv = *(const float4*)&ks_l[sb * 16 + s][kg * 16 + i4 * 4];
                float ka[4] = {kv.x, kv.y, kv.z, kv.w};
#pragma unroll
                for (int u = 0; u < 4; ++u) {
                    acc[i4 * 4 + u][0] += ka[u] * vv.x;
                    acc[i4 * 4 + u][1] += ka[u] * vv.y;
                    acc[i4 * 4 + u][2] += ka[u] * vv.z;
                    acc[i4 * 4 + u][3] += ka[u] * vv.w;
                }
            }
        }
    }
#pragma unroll
    for (int i = 0; i < 16; ++i) {
        int k = kg * 16 + i;
        float4 o = {acc[i][0], acc[i][1], acc[i][2], acc[i][3]};
        *(float4*)&O[(((size_t)c * B_DIM + b) * K_DIM + k) * E_DIM + es * 256 + ex * 4] = o;
    }
}

// ---------------------------------------------------------------------------
// Pass B: exclusive prefix over chunks: S_c = sum_{c'<c} O_c'
// ---------------------------------------------------------------------------
__global__ __launch_bounds__(256) void prefix_state(const float* __restrict__ O,
                                                    float* __restrict__ S) {
    const size_t p = (size_t)blockIdx.x * 256 + threadIdx.x;
    const size_t off = p * 4;
    const size_t cs = (size_t)B_DIM * K_DIM * E_DIM;
    float4 run = {0.f, 0.f, 0.f, 0.f};
    for (int c = 0; c < NC; ++c) {
        *(float4*)&S[c * cs + off] = run;
        float4 o = *(const float4*)&O[c * cs + off];
        run.x += o.x; run.y += o.y; run.z += o.z; run.w += o.w;
    }
}

// ---------------------------------------------------------------------------
// Pass C2: intra-chunk causal part (unscaled).
// ---------------------------------------------------------------------------
__global__ __launch_bounds__(256) void intra_attn(const float* __restrict__ QN,
                                                  const float* __restrict__ KN,
                                                  const float* __restrict__ V,
                                                  float* __restrict__ OUT) {
    __shared__ __align__(16) float qs[32][68];
    __shared__ __align__(16) float ks[32][68];
    __shared__ float sc[32][33];
    const int qt = blockIdx.x;
    const int ec = blockIdx.y;
    const int b = blockIdx.z;
    const int tid = threadIdx.x;
    const int tx = tid & 31;
    const int ty = tid >> 5;

    for (int l = tid; l < 32 * 64; l += 256) {
        int qq = l >> 6, k = l & 63;
        qs[qq][k] = QN[((size_t)(qt * 32 + qq) * B_DIM + b) * K_DIM + k];
    }
    float acc[4][8];
#pragma unroll
    for (int i = 0; i < 4; ++i)
#pragma unroll
        for (int j = 0; j < 8; ++j) acc[i][j] = 0.f;

    const int st0 = qt & ~3;
    for (int st = st0; st <= qt; ++st) {
        __syncthreads();
        for (int l = tid; l < 32 * 64; l += 256) {
            int ss = l >> 6, k = l & 63;
            ks[ss][k] = KN[((size_t)(st * 32 + ss) * B_DIM + b) * K_DIM + k];
        }
        __syncthreads();
#pragma unroll
        for (int i = 0; i < 4; ++i) {
            int p = tid + i * 256;
            int qq = p & 31, ss = p >> 5;
            float d = 0.f;
#pragma unroll
            for (int k = 0; k < 64; k += 4) {
                float4 a = *(const float4*)&qs[qq][k];
                float4 kb = *(const float4*)&ks[ss][k];
                d += a.x * kb.x + a.y * kb.y + a.z * kb.z + a.w * kb.w;
            }
            int tg = qt * 32 + qq, sg = st * 32 + ss;
            sc[qq][ss] = (sg <= tg) ? d : 0.f;
        }
        __syncthreads();
        const float* vbase =
            V + ((size_t)(st * 32) * B_DIM + b) * E_DIM + ec * 256 + tx * 8;
#pragma unroll 4
        for (int ss = 0; ss < 32; ++ss) {
            float a0 = sc[ty * 4 + 0][ss];
            float a1 = sc[ty * 4 + 1][ss];
            float a2 = sc[ty * 4 + 2][ss];
            float a3 = sc[ty * 4 + 3][ss];
            const float* vp = vbase + (size_t)ss * B_DIM * E_DIM;
            float4 v0 = *(const float4*)vp;
            float4 v1 = *(const float4*)(vp + 4);
            float av[8] = {v0.x, v0.y, v0.z, v0.w, v1.x, v1.y, v1.z, v1.w};
#pragma unroll
            for (int j = 0; j < 8; ++j) {
                acc[0][j] += a0 * av[j];
                acc[1][j] += a1 * av[j];
                acc[2][j] += a2 * av[j];
                acc[3][j] += a3 * av[j];
            }
        }
        __syncthreads();
    }
#pragma unroll
    for (int i = 0; i < 4; ++i) {
        int t = qt * 32 + ty * 4 + i;
        float* o = OUT + ((size_t)t * B_DIM + b) * E_DIM + ec * 256 + tx * 8;
        float4 o0 = {acc[i][0], acc[i][1], acc[i][2], acc[i][3]};
        float4 o1 = {acc[i][4], acc[i][5], acc[i][6], acc[i][7]};
        *(float4*)o = o0;
        *(float4*)(o + 4) = o1;
    }
}

// ---------------------------------------------------------------------------
// Pass C1: out = (out + qn @ S_chunk(t)) * rsqrt(t+1)
// ---------------------------------------------------------------------------
__global__ __launch_bounds__(256) void inter_add(const float* __restrict__ QN,
                                                 const float* __restrict__ S,
                                                 float* __restrict__ OUT) {
    __shared__ __align__(16) float Sl[64][128];
    __shared__ __align__(16) float qs[64][64];
    const int tt = blockIdx.x;
    const int es = blockIdx.y;
    const int b = blockIdx.z;
    const int tid = threadIdx.x;
    const int ex = tid & 31;
    const int tg = tid >> 5;
    const int t0 = tt * 64;
    const int c = t0 / CHUNK;
    const size_t cs = (size_t)B_DIM * K_DIM * E_DIM;

#pragma unroll
    for (int j = 0; j < 8; ++j) {
        int idx = tid + j * 256;
        int k = idx >> 5, e4 = idx & 31;
        *(float4*)&Sl[k][e4 * 4] =
            *(const float4*)&S[c * cs + ((size_t)b * K_DIM + k) * E_DIM + es * 128 + e4 * 4];
    }
#pragma unroll
    for (int j = 0; j < 4; ++j) {
        int idx = tid + j * 256;
        int t = idx >> 4, k4 = idx & 15;
        *(float4*)&qs[t][k4 * 4] =
            *(const float4*)&QN[((size_t)(t0 + t) * B_DIM + b) * K_DIM + k4 * 4];
    }
    __syncthreads();

    float acc[8][4];
#pragma unroll
    for (int i = 0; i < 8; ++i)
#pragma unroll
        for (int j = 0; j < 4; ++j) acc[i][j] = 0.f;

#pragma unroll 4
    for (int k = 0; k < 64; k += 4) {
        float4 sv0 = *(const float4*)&Sl[k + 0][ex * 4];
        float4 sv1 = *(const float4*)&Sl[k + 1][ex * 4];
        float4 sv2 = *(const float4*)&Sl[k + 2][ex * 4];
        float4 sv3 = *(const float4*)&Sl[k + 3][ex * 4];
#pragma unroll
        for (int i = 0; i < 8; ++i) {
            float4 qv = *(const float4*)&qs[tg * 8 + i][k];
            acc[i][0] += qv.x * sv0.x + qv.y * sv1.x + qv.z * sv2.x + qv.w * sv3.x;
            acc[i][1] += qv.x * sv0.y + qv.y * sv1.y + qv.z * sv2.y + qv.w * sv3.y;
            acc[i][2] += qv.x * sv0.z + qv.y * sv1.z + qv.z * sv2.z + qv.w * sv3.z;
            acc[i][3] += qv.x * sv0.w + qv.y * sv1.w + qv.z * sv2.w + qv.w * sv3.w;
        }
    }
#pragma unroll
    for (int i = 0; i < 8; ++i) {
        int t = t0 + tg * 8 + i;
        float sca = rsqrtf((float)(t + 1));
        float* o = OUT + ((size_t)t * B_DIM + b) * E_DIM + es * 128 + ex * 4;
        float4 prev = *(const float4*)o;
        float4 r;
        r.x = (prev.x + acc[i][0]) * sca;
        r.y = (prev.y + acc[i][1]) * sca;
        r.z = (prev.z + acc[i][2]) * sca;
        r.w = (prev.w + acc[i][3]) * sca;
        *(float4*)o = r;
    }
}

// ---------------------------------------------------------------------------
extern "C" void kernel_launch(void* const* d_in, const int* in_sizes, int n_in,
                              void* d_out, int out_size, void* d_ws,
                              size_t ws_size, hipStream_t stream) {
    const float* x = (const float*)d_in[0];
    const float* Wq = (const float*)d_in[2];
    const float* bq = (const float*)d_in[3];
    const float* Wk = (const float*)d_in[4];
    const float* bk = (const float*)d_in[5];
    const float* Wv = (const float*)d_in[6];
    const float* bv = (const float*)d_in[7];
    const float* kg = (const float*)d_in[8];
    const float* kb = (const float*)d_in[9];
    const float* vg = (const float*)d_in[10];
    const float* vb = (const float*)d_in[11];
    float* out = (float*)d_out;

    float* ws = (float*)d_ws;
    float* qraw = ws;                              // 4M floats (16 MB)
    float* v = ws + (size_t)4 * 1024 * 1024;       // 4M floats (16 MB)
    float* qn = ws + (size_t)8 * 1024 * 1024;      // 256K floats
    float* kn = qn + 256 * 1024;                   // 256K floats
    float* kraw = kn + 256 * 1024;                 // 256K floats
    __bf16* xb = (__bf16*)(kraw + 256 * 1024);     // 4M bf16 (8 MB)
    __bf16* wb = xb + (size_t)4 * 1024 * 1024;     // 2M bf16 (4 MB)
    // qraw is free after softmax_mean: reuse for chunk states
    float* O = qraw;                               // NC*B*K*E = 2M floats
    float* S = qraw + (size_t)2 * 1024 * 1024;     // 2M floats

    // bf16 conversions
    cvt_pair<<<dim3(2048), 256, 0, stream>>>(x, x, (size_t)4 * 1024 * 1024, xb);
    cvt_pair<<<dim3(1024), 256, 0, stream>>>(Wq, Wv, (size_t)1024 * 1024, wb);
    // projections: q&v via MFMA, k via fp32 (small, precision-critical path)
    gemm_mfma<<<dim3(32, 16), 256, 0, stream>>>(xb, wb, bq, bv, qraw, v);
    gemm_bias<<<dim3(R_DIM / 64, 1), 256, 0, stream>>>(x, Wk, bk, kraw, K_DIM);
    // epilogues
    softmax_mean<<<dim3(R_DIM), 64, 0, stream>>>(qraw, qn);
    ln64<<<dim3(R_DIM), 64, 0, stream>>>(kraw, kg, kb, kn);
    ln1024<<<dim3(R_DIM), 256, 0, stream>>>(v, vg, vb);
    // chunked linear attention
    chunk_outer<<<dim3(NC, 4, B_DIM), 256, 0, stream>>>(kn, v, O);
    prefix_state<<<dim3(128), 256, 0, stream>>>(O, S);
    intra_attn<<<dim3(64, 4, B_DIM), 256, 0, stream>>>(qn, kn, v, out);
    inter_add<<<dim3(32, 8, B_DIM), 256, 0, stream>>>(qn, S, out);
}

// Round 4
// 241.842 us; speedup vs baseline: 4.5728x; 1.2493x over previous
//
#include <hip/hip_runtime.h>
#include <math.h>

#define T_DIM 2048
#define B_DIM 2
#define E_DIM 1024
#define K_DIM 64
#define H_DIM 16
#define R_DIM (T_DIM * B_DIM)   // 4096 rows, row r = t*B + b
#define CHUNK 128               // state chunk (4 sub-tiles of 32)
#define NC (T_DIM / CHUNK)      // 16 chunks
#define WROWS 2176              // Wq(1024) + Wv(1024) + Wk(64) + pad(64)

typedef __bf16 bf16x8 __attribute__((ext_vector_type(8)));
typedef float f32x4 __attribute__((ext_vector_type(4)));

// ---------------------------------------------------------------------------
// fp32 -> bf16: x (4M elements), 8 per thread.
// ---------------------------------------------------------------------------
__global__ __launch_bounds__(256) void cvt_x(const float* __restrict__ X,
                                             __bf16* __restrict__ O) {
    size_t g = ((size_t)blockIdx.x * 256 + threadIdx.x) * 8;
    float4 a = *(const float4*)&X[g];
    float4 b = *(const float4*)&X[g + 4];
    bf16x8 o;
    o[0] = (__bf16)a.x; o[1] = (__bf16)a.y; o[2] = (__bf16)a.z; o[3] = (__bf16)a.w;
    o[4] = (__bf16)b.x; o[5] = (__bf16)b.y; o[6] = (__bf16)b.z; o[7] = (__bf16)b.w;
    *(bf16x8*)&O[g] = o;
}

// ---------------------------------------------------------------------------
// fp32 -> bf16 weight concat: [Wq(1024 rows); Wv(1024); Wk(64); zeros(64)],
// all rows are length-1024. Region boundaries are multiples of 8.
// ---------------------------------------------------------------------------
__global__ __launch_bounds__(256) void cvt_w(const float* __restrict__ Wq,
                                             const float* __restrict__ Wv,
                                             const float* __restrict__ Wk,
                                             __bf16* __restrict__ O) {
    const size_t nq = (size_t)1024 * 1024;
    const size_t nk = (size_t)64 * 1024;
    size_t g = ((size_t)blockIdx.x * 256 + threadIdx.x) * 8;
    bf16x8 o;
    if (g < 2 * nq + nk) {
        const float* src;
        size_t off;
        if (g < nq)          { src = Wq; off = g; }
        else if (g < 2 * nq) { src = Wv; off = g - nq; }
        else                 { src = Wk; off = g - 2 * nq; }
        float4 a = *(const float4*)&src[off];
        float4 b = *(const float4*)&src[off + 4];
        o[0] = (__bf16)a.x; o[1] = (__bf16)a.y; o[2] = (__bf16)a.z; o[3] = (__bf16)a.w;
        o[4] = (__bf16)b.x; o[5] = (__bf16)b.y; o[6] = (__bf16)b.z; o[7] = (__bf16)b.w;
    } else {
#pragma unroll
        for (int i = 0; i < 8; ++i) o[i] = (__bf16)0.f;
    }
    *(bf16x8*)&O[g] = o;
}

// ---------------------------------------------------------------------------
// bf16 MFMA GEMM: C[4096 x 2176] = XB[4096x1024] @ WB[2176x1024]^T
// 128x128 tile, BK=32, 4 waves each owning 64x64 (4x4 MFMA tiles 16x16x32).
// Cols <1024 -> Cq(+bq); <2048 -> Cv(+bv); else first 64 -> Kr(+bk, stride 64).
// ---------------------------------------------------------------------------
__global__ __launch_bounds__(256) void gemm_mfma(const __bf16* __restrict__ XB,
                                                 const __bf16* __restrict__ WB,
                                                 const float* __restrict__ bq,
                                                 const float* __restrict__ bv,
                                                 const float* __restrict__ bk,
                                                 float* __restrict__ Cq,
                                                 float* __restrict__ Cv,
                                                 float* __restrict__ Kr) {
    __shared__ __bf16 Als[128 * 32];   // 8 KB
    __shared__ __bf16 Bls[128 * 32];   // 8 KB
    const int tid = threadIdx.x;
    const int lane = tid & 63;
    const int w = tid >> 6;
    const int wm = (w & 1) * 64;
    const int wn = (w >> 1) * 64;
    const int rBase = blockIdx.x * 128;
    const int cBase = blockIdx.y * 128;

    const int c0 = tid, c1 = tid + 256;
    const __bf16* gA0 = XB + (size_t)(rBase + (c0 >> 2)) * E_DIM + (c0 & 3) * 8;
    const __bf16* gA1 = XB + (size_t)(rBase + (c1 >> 2)) * E_DIM + (c1 & 3) * 8;
    const __bf16* gB0 = WB + (size_t)(cBase + (c0 >> 2)) * E_DIM + (c0 & 3) * 8;
    const __bf16* gB1 = WB + (size_t)(cBase + (c1 >> 2)) * E_DIM + (c1 & 3) * 8;
    __bf16* lA0 = Als + c0 * 8;
    __bf16* lA1 = Als + c1 * 8;
    __bf16* lB0 = Bls + c0 * 8;
    __bf16* lB1 = Bls + c1 * 8;

    const int fr = lane & 15;
    const int fk = (lane >> 4) * 8;
    const __bf16* aF = Als + (wm + fr) * 32 + fk;
    const __bf16* bF = Bls + (wn + fr) * 32 + fk;

    f32x4 acc[4][4] = {};

    for (int kk = 0; kk < E_DIM; kk += 32) {
        __syncthreads();
        __builtin_amdgcn_global_load_lds(
            (const __attribute__((address_space(1))) void*)(gA0 + kk),
            (__attribute__((address_space(3))) void*)lA0, 16, 0, 0);
        __builtin_amdgcn_global_load_lds(
            (const __attribute__((address_space(1))) void*)(gA1 + kk),
            (__attribute__((address_space(3))) void*)lA1, 16, 0, 0);
        __builtin_amdgcn_global_load_lds(
            (const __attribute__((address_space(1))) void*)(gB0 + kk),
            (__attribute__((address_space(3))) void*)lB0, 16, 0, 0);
        __builtin_amdgcn_global_load_lds(
            (const __attribute__((address_space(1))) void*)(gB1 + kk),
            (__attribute__((address_space(3))) void*)lB1, 16, 0, 0);
        __syncthreads();

        bf16x8 af[4], bfr[4];
#pragma unroll
        for (int mt = 0; mt < 4; ++mt) af[mt] = *(const bf16x8*)(aF + mt * 16 * 32);
#pragma unroll
        for (int nt = 0; nt < 4; ++nt) bfr[nt] = *(const bf16x8*)(bF + nt * 16 * 32);
#pragma unroll
        for (int mt = 0; mt < 4; ++mt)
#pragma unroll
            for (int nt = 0; nt < 4; ++nt)
                acc[mt][nt] = __builtin_amdgcn_mfma_f32_16x16x32_bf16(
                    af[mt], bfr[nt], acc[mt][nt], 0, 0, 0);
    }

    // epilogue: C/D layout col=lane&15, row=(lane>>4)*4+reg
    const int row0 = rBase + wm + (lane >> 4) * 4;
    if (cBase < 2048) {
        const float* bias;
        float* Cout;
        int colBase;
        if (cBase < 1024) { bias = bq; Cout = Cq; colBase = cBase; }
        else              { bias = bv; Cout = Cv; colBase = cBase - 1024; }
        const int col0 = colBase + wn + (lane & 15);
#pragma unroll
        for (int mt = 0; mt < 4; ++mt)
#pragma unroll
            for (int nt = 0; nt < 4; ++nt) {
                int cc = col0 + nt * 16;
                float bb = bias[cc];
#pragma unroll
                for (int r = 0; r < 4; ++r)
                    Cout[(size_t)(row0 + mt * 16 + r) * E_DIM + cc] =
                        acc[mt][nt][r] + bb;
            }
    } else {
        // k block: only columns 0..63 are real (then zero-pad rows of WB)
        const int col0 = wn + (lane & 15);
#pragma unroll
        for (int mt = 0; mt < 4; ++mt)
#pragma unroll
            for (int nt = 0; nt < 4; ++nt) {
                int cc = col0 + nt * 16;
                if (cc < 64) {
                    float bb = bk[cc];
#pragma unroll
                    for (int r = 0; r < 4; ++r)
                        Kr[(size_t)(row0 + mt * 16 + r) * K_DIM + cc] =
                            acc[mt][nt][r] + bb;
                }
            }
    }
}

// ---------------------------------------------------------------------------
// qn[r, k] = mean_h softmax_k(q[r, h*64 + k]) ; one wave per row.
// ---------------------------------------------------------------------------
__global__ __launch_bounds__(64) void softmax_mean(const float* __restrict__ Q,
                                                   float* __restrict__ QN) {
    const int r = blockIdx.x;
    const int lane = threadIdx.x;
    float acc = 0.f;
#pragma unroll
    for (int h = 0; h < H_DIM; ++h) {
        float v = Q[(size_t)r * 1024 + h * 64 + lane];
        float m = v;
#pragma unroll
        for (int off = 32; off; off >>= 1) m = fmaxf(m, __shfl_xor(m, off));
        float e = expf(v - m);
        float ssum = e;
#pragma unroll
        for (int off = 32; off; off >>= 1) ssum += __shfl_xor(ssum, off);
        acc += e / ssum;
    }
    QN[(size_t)r * K_DIM + lane] = acc * (1.f / 16.f);
}

// ---------------------------------------------------------------------------
// LayerNorm over 64 (for k); one wave per row.
// ---------------------------------------------------------------------------
__global__ __launch_bounds__(64) void ln64(const float* __restrict__ Kraw,
                                           const float* __restrict__ gamma,
                                           const float* __restrict__ beta,
                                           float* __restrict__ KN) {
    const int r = blockIdx.x;
    const int lane = threadIdx.x;
    float v = Kraw[(size_t)r * K_DIM + lane];
    float s = v, s2 = v * v;
#pragma unroll
    for (int off = 32; off; off >>= 1) {
        s += __shfl_xor(s, off);
        s2 += __shfl_xor(s2, off);
    }
    float mean = s * (1.f / 64.f);
    float var = s2 * (1.f / 64.f) - mean * mean;
    float inv = rsqrtf(var + 1e-5f);
    KN[(size_t)r * K_DIM + lane] = (v - mean) * inv * gamma[lane] + beta[lane];
}

// ---------------------------------------------------------------------------
// LayerNorm over 1024 (for v), in place. Block = 256 threads.
// ---------------------------------------------------------------------------
__global__ __launch_bounds__(256) void ln1024(float* __restrict__ V,
                                              const float* __restrict__ gamma,
                                              const float* __restrict__ beta) {
    const int r = blockIdx.x;
    const int tid = threadIdx.x;
    const int lane = tid & 63, wv = tid >> 6;
    float4 v = *(const float4*)&V[(size_t)r * E_DIM + tid * 4];
    float s = v.x + v.y + v.z + v.w;
    float s2 = v.x * v.x + v.y * v.y + v.z * v.z + v.w * v.w;
#pragma unroll
    for (int off = 32; off; off >>= 1) {
        s += __shfl_xor(s, off);
        s2 += __shfl_xor(s2, off);
    }
    __shared__ float red[2][4];
    if (lane == 0) { red[0][wv] = s; red[1][wv] = s2; }
    __syncthreads();
    s = red[0][0] + red[0][1] + red[0][2] + red[0][3];
    s2 = red[1][0] + red[1][1] + red[1][2] + red[1][3];
    float mean = s * (1.f / 1024.f);
    float var = s2 * (1.f / 1024.f) - mean * mean;
    float inv = rsqrtf(var + 1e-5f);
    float4 g = *(const float4*)&gamma[tid * 4];
    float4 bb = *(const float4*)&beta[tid * 4];
    float4 o;
    o.x = (v.x - mean) * inv * g.x + bb.x;
    o.y = (v.y - mean) * inv * g.y + bb.y;
    o.z = (v.z - mean) * inv * g.z + bb.z;
    o.w = (v.w - mean) * inv * g.w + bb.w;
    *(float4*)&V[(size_t)r * E_DIM + tid * 4] = o;
}

// ---------------------------------------------------------------------------
// Pass A: per-chunk outer products O_c[b][k][e] = sum_{s in chunk} kn[s,k]*v[s,e]
// ---------------------------------------------------------------------------
__global__ __launch_bounds__(256) void chunk_outer(const float* __restrict__ KN,
                                                   const float* __restrict__ V,
                                                   float* __restrict__ O) {
    __shared__ __align__(16) float ks_l[CHUNK][64];   // 32 KB
    __shared__ __align__(16) float vs[16][256];       // 16 KB
    const int c = blockIdx.x, es = blockIdx.y, b = blockIdx.z;
    const int tid = threadIdx.x;
    const int ex = tid & 63;     // e = es*256 + ex*4
    const int kg = tid >> 6;     // k rows kg*16 .. +15

#pragma unroll
    for (int j = 0; j < 8; ++j) {
        int idx = tid + j * 256;
        int s = idx >> 4, k4 = idx & 15;
        *(float4*)&ks_l[s][k4 * 4] =
            *(const float4*)&KN[((size_t)(c * CHUNK + s) * B_DIM + b) * K_DIM + k4 * 4];
    }
    float acc[16][4];
#pragma unroll
    for (int i = 0; i < 16; ++i)
#pragma unroll
        for (int j = 0; j < 4; ++j) acc[i][j] = 0.f;

    for (int sb = 0; sb < CHUNK / 16; ++sb) {
        __syncthreads();
#pragma unroll
        for (int j = 0; j < 4; ++j) {
            int idx = tid + j * 256;
            int s = idx >> 6, e4 = idx & 63;
            *(float4*)&vs[s][e4 * 4] =
                *(const float4*)&V[((size_t)(c * CHUNK + sb * 16 + s) * B_DIM + b) * E_DIM +
                                   es * 256 + e4 * 4];
        }
        __syncthreads();
#pragma unroll
        for (int s = 0; s < 16; ++s) {
            float4 vv = *(const float4*)&vs[s][ex * 4];
#pragma unroll
            for (int i4 = 0; i4 < 4; ++i4) {
                float4 kv = *(const float4*)&ks_l[sb * 16 + s][kg * 16 + i4 * 4];
                float ka[4] = {kv.x, kv.y, kv.z, kv.w};
#pragma unroll
                for (int u = 0; u < 4; ++u) {
                    acc[i4 * 4 + u][0] += ka[u] * vv.x;
                    acc[i4 * 4 + u][1] += ka[u] * vv.y;
                    acc[i4 * 4 + u][2] += ka[u] * vv.z;
                    acc[i4 * 4 + u][3] += ka[u] * vv.w;
                }
            }
        }
    }
#pragma unroll
    for (int i = 0; i < 16; ++i) {
        int k = kg * 16 + i;
        float4 o = {acc[i][0], acc[i][1], acc[i][2], acc[i][3]};
        *(float4*)&O[(((size_t)c * B_DIM + b) * K_DIM + k) * E_DIM + es * 256 + ex * 4] = o;
    }
}

// ---------------------------------------------------------------------------
// Pass B: exclusive prefix over chunks: S_c = sum_{c'<c} O_c'
// ---------------------------------------------------------------------------
__global__ __launch_bounds__(256) void prefix_state(const float* __restrict__ O,
                                                    float* __restrict__ S) {
    const size_t p = (size_t)blockIdx.x * 256 + threadIdx.x;
    const size_t off = p * 4;
    const size_t cs = (size_t)B_DIM * K_DIM * E_DIM;
    float4 run = {0.f, 0.f, 0.f, 0.f};
    for (int c = 0; c < NC; ++c) {
        *(float4*)&S[c * cs + off] = run;
        float4 o = *(const float4*)&O[c * cs + off];
        run.x += o.x; run.y += o.y; run.z += o.z; run.w += o.w;
    }
}

// ---------------------------------------------------------------------------
// Pass C2: intra-chunk causal part (unscaled).
// ---------------------------------------------------------------------------
__global__ __launch_bounds__(256) void intra_attn(const float* __restrict__ QN,
                                                  const float* __restrict__ KN,
                                                  const float* __restrict__ V,
                                                  float* __restrict__ OUT) {
    __shared__ __align__(16) float qs[32][68];
    __shared__ __align__(16) float ks[32][68];
    __shared__ float sc[32][33];
    const int qt = blockIdx.x;
    const int ec = blockIdx.y;
    const int b = blockIdx.z;
    const int tid = threadIdx.x;
    const int tx = tid & 31;
    const int ty = tid >> 5;

    for (int l = tid; l < 32 * 64; l += 256) {
        int qq = l >> 6, k = l & 63;
        qs[qq][k] = QN[((size_t)(qt * 32 + qq) * B_DIM + b) * K_DIM + k];
    }
    float acc[4][8];
#pragma unroll
    for (int i = 0; i < 4; ++i)
#pragma unroll
        for (int j = 0; j < 8; ++j) acc[i][j] = 0.f;

    const int st0 = qt & ~3;
    for (int st = st0; st <= qt; ++st) {
        __syncthreads();
        for (int l = tid; l < 32 * 64; l += 256) {
            int ss = l >> 6, k = l & 63;
            ks[ss][k] = KN[((size_t)(st * 32 + ss) * B_DIM + b) * K_DIM + k];
        }
        __syncthreads();
#pragma unroll
        for (int i = 0; i < 4; ++i) {
            int p = tid + i * 256;
            int qq = p & 31, ss = p >> 5;
            float d = 0.f;
#pragma unroll
            for (int k = 0; k < 64; k += 4) {
                float4 a = *(const float4*)&qs[qq][k];
                float4 kb = *(const float4*)&ks[ss][k];
                d += a.x * kb.x + a.y * kb.y + a.z * kb.z + a.w * kb.w;
            }
            int tg = qt * 32 + qq, sg = st * 32 + ss;
            sc[qq][ss] = (sg <= tg) ? d : 0.f;
        }
        __syncthreads();
        const float* vbase =
            V + ((size_t)(st * 32) * B_DIM + b) * E_DIM + ec * 256 + tx * 8;
#pragma unroll 4
        for (int ss = 0; ss < 32; ++ss) {
            float a0 = sc[ty * 4 + 0][ss];
            float a1 = sc[ty * 4 + 1][ss];
            float a2 = sc[ty * 4 + 2][ss];
            float a3 = sc[ty * 4 + 3][ss];
            const float* vp = vbase + (size_t)ss * B_DIM * E_DIM;
            float4 v0 = *(const float4*)vp;
            float4 v1 = *(const float4*)(vp + 4);
            float av[8] = {v0.x, v0.y, v0.z, v0.w, v1.x, v1.y, v1.z, v1.w};
#pragma unroll
            for (int j = 0; j < 8; ++j) {
                acc[0][j] += a0 * av[j];
                acc[1][j] += a1 * av[j];
                acc[2][j] += a2 * av[j];
                acc[3][j] += a3 * av[j];
            }
        }
        __syncthreads();
    }
#pragma unroll
    for (int i = 0; i < 4; ++i) {
        int t = qt * 32 + ty * 4 + i;
        float* o = OUT + ((size_t)t * B_DIM + b) * E_DIM + ec * 256 + tx * 8;
        float4 o0 = {acc[i][0], acc[i][1], acc[i][2], acc[i][3]};
        float4 o1 = {acc[i][4], acc[i][5], acc[i][6], acc[i][7]};
        *(float4*)o = o0;
        *(float4*)(o + 4) = o1;
    }
}

// ---------------------------------------------------------------------------
// Pass C1: out = (out + qn @ S_chunk(t)) * rsqrt(t+1)
// ---------------------------------------------------------------------------
__global__ __launch_bounds__(256) void inter_add(const float* __restrict__ QN,
                                                 const float* __restrict__ S,
                                                 float* __restrict__ OUT) {
    __shared__ __align__(16) float Sl[64][128];
    __shared__ __align__(16) float qs[64][64];
    const int tt = blockIdx.x;
    const int es = blockIdx.y;
    const int b = blockIdx.z;
    const int tid = threadIdx.x;
    const int ex = tid & 31;
    const int tg = tid >> 5;
    const int t0 = tt * 64;
    const int c = t0 / CHUNK;
    const size_t cs = (size_t)B_DIM * K_DIM * E_DIM;

#pragma unroll
    for (int j = 0; j < 8; ++j) {
        int idx = tid + j * 256;
        int k = idx >> 5, e4 = idx & 31;
        *(float4*)&Sl[k][e4 * 4] =
            *(const float4*)&S[c * cs + ((size_t)b * K_DIM + k) * E_DIM + es * 128 + e4 * 4];
    }
#pragma unroll
    for (int j = 0; j < 4; ++j) {
        int idx = tid + j * 256;
        int t = idx >> 4, k4 = idx & 15;
        *(float4*)&qs[t][k4 * 4] =
            *(const float4*)&QN[((size_t)(t0 + t) * B_DIM + b) * K_DIM + k4 * 4];
    }
    __syncthreads();

    float acc[8][4];
#pragma unroll
    for (int i = 0; i < 8; ++i)
#pragma unroll
        for (int j = 0; j < 4; ++j) acc[i][j] = 0.f;

#pragma unroll 4
    for (int k = 0; k < 64; k += 4) {
        float4 sv0 = *(const float4*)&Sl[k + 0][ex * 4];
        float4 sv1 = *(const float4*)&Sl[k + 1][ex * 4];
        float4 sv2 = *(const float4*)&Sl[k + 2][ex * 4];
        float4 sv3 = *(const float4*)&Sl[k + 3][ex * 4];
#pragma unroll
        for (int i = 0; i < 8; ++i) {
            float4 qv = *(const float4*)&qs[tg * 8 + i][k];
            acc[i][0] += qv.x * sv0.x + qv.y * sv1.x + qv.z * sv2.x + qv.w * sv3.x;
            acc[i][1] += qv.x * sv0.y + qv.y * sv1.y + qv.z * sv2.y + qv.w * sv3.y;
            acc[i][2] += qv.x * sv0.z + qv.y * sv1.z + qv.z * sv2.z + qv.w * sv3.z;
            acc[i][3] += qv.x * sv0.w + qv.y * sv1.w + qv.z * sv2.w + qv.w * sv3.w;
        }
    }
#pragma unroll
    for (int i = 0; i < 8; ++i) {
        int t = t0 + tg * 8 + i;
        float sca = rsqrtf((float)(t + 1));
        float* o = OUT + ((size_t)t * B_DIM + b) * E_DIM + es * 128 + ex * 4;
        float4 prev = *(const float4*)o;
        float4 r;
        r.x = (prev.x + acc[i][0]) * sca;
        r.y = (prev.y + acc[i][1]) * sca;
        r.z = (prev.z + acc[i][2]) * sca;
        r.w = (prev.w + acc[i][3]) * sca;
        *(float4*)o = r;
    }
}

// ---------------------------------------------------------------------------
extern "C" void kernel_launch(void* const* d_in, const int* in_sizes, int n_in,
                              void* d_out, int out_size, void* d_ws,
                              size_t ws_size, hipStream_t stream) {
    const float* x = (const float*)d_in[0];
    const float* Wq = (const float*)d_in[2];
    const float* bq = (const float*)d_in[3];
    const float* Wk = (const float*)d_in[4];
    const float* bk = (const float*)d_in[5];
    const float* Wv = (const float*)d_in[6];
    const float* bv = (const float*)d_in[7];
    const float* kg = (const float*)d_in[8];
    const float* kb = (const float*)d_in[9];
    const float* vg = (const float*)d_in[10];
    const float* vb = (const float*)d_in[11];
    float* out = (float*)d_out;

    float* ws = (float*)d_ws;
    float* qraw = ws;                              // 4M floats (16 MB)
    float* v = ws + (size_t)4 * 1024 * 1024;       // 4M floats (16 MB)
    float* qn = ws + (size_t)8 * 1024 * 1024;      // 256K floats
    float* kn = qn + 256 * 1024;                   // 256K floats
    float* kraw = kn + 256 * 1024;                 // 256K floats
    __bf16* xb = (__bf16*)(kraw + 256 * 1024);     // 4M bf16 (8 MB)
    __bf16* wb = xb + (size_t)4 * 1024 * 1024;     // 2176*1024 bf16 (4.46 MB)
    // qraw is free after softmax_mean: reuse for chunk states
    float* O = qraw;                               // NC*B*K*E = 2M floats
    float* S = qraw + (size_t)2 * 1024 * 1024;     // 2M floats

    // bf16 conversions
    cvt_x<<<dim3(2048), 256, 0, stream>>>(x, xb);
    cvt_w<<<dim3(WROWS * 1024 / 8 / 256), 256, 0, stream>>>(Wq, Wv, Wk, wb);
    // fused q|v|k projection via MFMA
    gemm_mfma<<<dim3(32, 17), 256, 0, stream>>>(xb, wb, bq, bv, bk, qraw, v, kraw);
    // epilogues
    softmax_mean<<<dim3(R_DIM), 64, 0, stream>>>(qraw, qn);
    ln64<<<dim3(R_DIM), 64, 0, stream>>>(kraw, kg, kb, kn);
    ln1024<<<dim3(R_DIM), 256, 0, stream>>>(v, vg, vb);
    // chunked linear attention
    chunk_outer<<<dim3(NC, 4, B_DIM), 256, 0, stream>>>(kn, v, O);
    prefix_state<<<dim3(128), 256, 0, stream>>>(O, S);
    intra_attn<<<dim3(64, 4, B_DIM), 256, 0, stream>>>(qn, kn, v, out);
    inter_add<<<dim3(32, 8, B_DIM), 256, 0, stream>>>(qn, S, out);
}